// Round 3
// baseline (1663.648 us; speedup 1.0000x reference)
//
#include <hip/hip_runtime.h>
#include <stdint.h>

// GCN 2-layer forward via dst-bucketed edges + LDS tile accumulation.
// bucket = dst >> 9 (512 nodes/tile). Edges packed as (local_dst<<18)|src (u32).
// No global fp32 atomics anywhere; no fine-grained CSR.

#define TPB 256
#define TILE 512          // nodes per bucket
#define TILE_SHIFT 9
#define MAXB 512          // max buckets supported (N <= 262144)
#define AGU 8             // unroll in k_agg1

__global__ void k_zero_i(int* __restrict__ p, int m) {
    int i = blockIdx.x * TPB + threadIdx.x;
    if (i < m) p[i] = 0;
}

// per-bucket global histogram (LDS-staged)
__global__ __launch_bounds__(TPB) void k_bhist(const int* __restrict__ dst,
                                               int* __restrict__ bcnt, int e, int nb) {
    __shared__ int h[MAXB];
    for (int i = threadIdx.x; i < MAXB; i += TPB) h[i] = 0;
    __syncthreads();
    int stride = gridDim.x * TPB;
    for (int i = blockIdx.x * TPB + threadIdx.x; i < e; i += stride)
        atomicAdd(&h[dst[i] >> TILE_SHIFT], 1);
    __syncthreads();
    for (int i = threadIdx.x; i < nb; i += TPB)
        if (h[i]) atomicAdd(&bcnt[i], h[i]);
}

// single-block exclusive scan of bucket counts -> bstart, init bcursor
__global__ void k_bscan(const int* __restrict__ bcnt, int* __restrict__ bstart,
                        int* __restrict__ bcursor, int nb) {
    __shared__ int buf[2][MAXB];
    int t = threadIdx.x;
    int v = (t < nb) ? bcnt[t] : 0;
    buf[0][t] = v;
    __syncthreads();
    int cur = 0;
#pragma unroll
    for (int off = 1; off < MAXB; off <<= 1) {
        int nv = buf[cur][t] + (t >= off ? buf[cur][t - off] : 0);
        buf[cur ^ 1][t] = nv;
        __syncthreads();
        cur ^= 1;
    }
    int excl = buf[cur][t] - v;
    if (t < nb) { bstart[t] = excl; bcursor[t] = excl; }
    if (t == nb - 1) bstart[nb] = excl + v;
}

// block-local counting sort into per-bucket segments.
__global__ __launch_bounds__(1024) void k_bscatter(const int* __restrict__ src,
                                                   const int* __restrict__ dst,
                                                   int* __restrict__ bcursor,
                                                   uint32_t* __restrict__ bedges,
                                                   int e, int chunk) {
    __shared__ int hcnt[MAXB];
    __shared__ int hbase[MAXB];
    __shared__ int hpos[MAXB];
    int t = threadIdx.x;
    for (int i = t; i < MAXB; i += 1024) { hcnt[i] = 0; hpos[i] = 0; }
    __syncthreads();

    int e0 = blockIdx.x * chunk;
    int e1 = min(e0 + chunk, e);

    for (int i = e0 + t; i < e1; i += 1024)
        atomicAdd(&hcnt[dst[i] >> TILE_SHIFT], 1);
    __syncthreads();
    for (int i = t; i < MAXB; i += 1024)
        if (hcnt[i]) hbase[i] = atomicAdd(&bcursor[i], hcnt[i]);
    __syncthreads();
    for (int i = e0 + t; i < e1; i += 1024) {
        int d = dst[i];
        int b = d >> TILE_SHIFT;
        int lp = atomicAdd(&hpos[b], 1);
        bedges[hbase[b] + lp] = ((uint32_t)(d & (TILE - 1)) << 18) | (uint32_t)src[i];
    }
}

// per-bucket in-degree from bucketed edges -> dis = rsqrt(deg+1)
__global__ __launch_bounds__(1024) void k_bdeg(const uint32_t* __restrict__ bedges,
                                               const int* __restrict__ bstart,
                                               float* __restrict__ dis, int n) {
    __shared__ int deg[TILE];
    int t = threadIdx.x;
    if (t < TILE) deg[t] = 0;
    __syncthreads();
    int b = blockIdx.x;
    int s0 = bstart[b], s1 = bstart[b + 1];
    for (int i = s0 + t; i < s1; i += 1024)
        atomicAdd(&deg[bedges[i] >> 18], 1);
    __syncthreads();
    if (t < TILE) {
        int d = (b << TILE_SHIFT) + t;
        if (d < n) dis[d] = rsqrtf((float)deg[t] + 1.0f);
    }
}

// h1w = (x @ W1) * dis[row].  8 rows x 32 ch per block; W1 in LDS.
__global__ __launch_bounds__(TPB) void k_gemm1h(const float* __restrict__ x,
                                                const float* __restrict__ W1,
                                                const float* __restrict__ dis,
                                                float* __restrict__ h1w, int n) {
    __shared__ float w[128 * 32];
    for (int i = threadIdx.x; i < 128 * 32; i += TPB) w[i] = W1[i];
    __syncthreads();

    int lane = threadIdx.x & 31;
    int row  = blockIdx.x * 8 + (threadIdx.x >> 5);
    if (row >= n) return;

    const float4* xr = (const float4*)(x + (size_t)row * 128);
    float acc = 0.0f;
#pragma unroll
    for (int k4 = 0; k4 < 32; ++k4) {
        float4 xv = xr[k4];
        acc = fmaf(xv.x, w[(k4 * 4 + 0) * 32 + lane], acc);
        acc = fmaf(xv.y, w[(k4 * 4 + 1) * 32 + lane], acc);
        acc = fmaf(xv.z, w[(k4 * 4 + 2) * 32 + lane], acc);
        acc = fmaf(xv.w, w[(k4 * 4 + 3) * 32 + lane], acc);
    }
    h1w[(size_t)row * 32 + lane] = acc * dis[row];
}

// Layer 1: LDS tile accumulate + fused self-loop/bias/relu/dropout/W2/dis.
// hw2[d] = (dropout(relu(dis[d]*(sum + h1w[d]) + b1)) @ W2) * dis[d]
__global__ __launch_bounds__(1024) void k_agg1(const uint32_t* __restrict__ bedges,
                                               const int* __restrict__ bstart,
                                               const float* __restrict__ dis,
                                               const float* __restrict__ h1w,
                                               const float* __restrict__ b1,
                                               const float* __restrict__ drop_u,
                                               const float* __restrict__ W2,
                                               float* __restrict__ hw2, int n) {
    __shared__ float acc[TILE * 32];   // 64 KB
    for (int i = threadIdx.x; i < TILE * 32; i += 1024) acc[i] = 0.0f;
    __syncthreads();

    int b  = blockIdx.x;
    int s0 = bstart[b], cnt = bstart[b + 1] - s0;
    const uint32_t* eb = bedges + s0;

    int g = threadIdx.x >> 5;          // 32 groups of 32 lanes
    int c = threadIdx.x & 31;

    for (int i0 = g * AGU; i0 < cnt; i0 += 32 * AGU) {
        float v[AGU];
        int   ld[AGU];
#pragma unroll
        for (int u = 0; u < AGU; ++u) {
            int idx = i0 + u;
            if (idx < cnt) {
                uint32_t p = eb[idx];
                ld[u] = (int)(p >> 18);
                v[u]  = h1w[(size_t)(p & 0x3FFFFu) * 32 + c];
            } else ld[u] = -1;
        }
#pragma unroll
        for (int u = 0; u < AGU; ++u)
            if (ld[u] >= 0) atomicAdd(&acc[ld[u] * 32 + c], v[u]);
    }
    __syncthreads();

    int base = b << TILE_SHIFT;
    for (int ld = g; ld < TILE; ld += 32) {
        int d = base + ld;
        if (d >= n) continue;          // uniform within the 32-lane group
        float dd = dis[d];
        float v = dd * (acc[ld * 32 + c] + h1w[(size_t)d * 32 + c]) + b1[c];
        v = fmaxf(v, 0.0f);
        v = (drop_u[(size_t)d * 32 + c] > 0.5f) ? v * 2.0f : 0.0f;
        float p0 = v * W2[c * 2 + 0];
        float p1 = v * W2[c * 2 + 1];
#pragma unroll
        for (int off = 16; off >= 1; off >>= 1) {
            p0 += __shfl_xor(p0, off, 32);
            p1 += __shfl_xor(p1, off, 32);
        }
        if (c == 0) {
            float2 o; o.x = p0 * dd; o.y = p1 * dd;
            ((float2*)hw2)[d] = o;
        }
    }
}

// Layer 2: tile accumulate over hw2 + self loop + bias -> out
__global__ __launch_bounds__(1024) void k_agg2(const uint32_t* __restrict__ bedges,
                                               const int* __restrict__ bstart,
                                               const float* __restrict__ dis,
                                               const float* __restrict__ hw2,
                                               const float* __restrict__ b2,
                                               float* __restrict__ out, int n) {
    __shared__ float acc2[TILE * 2];   // 4 KB
    int t = threadIdx.x;
    if (t < TILE * 2 - 1024) {}        // TILE*2 == 1024, one store each
    acc2[t] = 0.0f;
    __syncthreads();

    int b  = blockIdx.x;
    int s0 = bstart[b], s1 = bstart[b + 1];
    for (int i = s0 + t; i < s1; i += 1024) {
        uint32_t p = bedges[i];
        int s  = (int)(p & 0x3FFFFu);
        int ld = (int)(p >> 18);
        float2 hv = ((const float2*)hw2)[s];
        atomicAdd(&acc2[ld * 2 + 0], hv.x);
        atomicAdd(&acc2[ld * 2 + 1], hv.y);
    }
    __syncthreads();

    int ld = t >> 1, j = t & 1;
    int d = (b << TILE_SHIFT) + ld;
    if (d < n) out[(size_t)d * 2 + j] = dis[d] * (acc2[t] + hw2[(size_t)d * 2 + j]) + b2[j];
}

extern "C" void kernel_launch(void* const* d_in, const int* in_sizes, int n_in,
                              void* d_out, int out_size, void* d_ws, size_t ws_size,
                              hipStream_t stream) {
    const float* x     = (const float*)d_in[0];
    const int*   ei    = (const int*)d_in[1];
    const float* W1    = (const float*)d_in[2];
    const float* b1    = (const float*)d_in[3];
    const float* W2    = (const float*)d_in[4];
    const float* b2    = (const float*)d_in[5];
    const float* dropu = (const float*)d_in[6];
    float* out = (float*)d_out;

    const int N = in_sizes[0] / 128;
    const int E = in_sizes[1] / 2;
    const int* src = ei;
    const int* dst = ei + E;

    const int NB = (N + TILE - 1) >> TILE_SHIFT;   // 391 for N=200000

    // workspace: dis f32[N] | h1w f32[N*32] | hw2 f32[N*2] |
    //            bcnt i32[MAXB] | bstart i32[MAXB+1] | bcursor i32[MAXB] | bedges u32[E]
    float* dis = (float*)d_ws;
    float* h1w = dis + N;
    float* hw2 = h1w + (size_t)N * 32;
    int* bcnt    = (int*)(hw2 + (size_t)N * 2);
    int* bstart  = bcnt + MAXB;
    int* bcursor = bstart + (MAXB + 1);
    uint32_t* bedges = (uint32_t*)(bcursor + MAXB);

    const int chunk = (E + NB - 1) / NB;

    k_zero_i  <<<(MAXB + TPB - 1) / TPB, TPB, 0, stream>>>(bcnt, MAXB);
    k_bhist   <<<1024, TPB, 0, stream>>>(dst, bcnt, E, NB);
    k_bscan   <<<1, MAXB, 0, stream>>>(bcnt, bstart, bcursor, NB);
    k_bscatter<<<NB, 1024, 0, stream>>>(src, dst, bcursor, bedges, E, chunk);
    k_bdeg    <<<NB, 1024, 0, stream>>>(bedges, bstart, dis, N);
    k_gemm1h  <<<(N + 7) / 8, TPB, 0, stream>>>(x, W1, dis, h1w, N);
    k_agg1    <<<NB, 1024, 0, stream>>>(bedges, bstart, dis, h1w, b1, dropu, W2, hw2, N);
    k_agg2    <<<NB, 1024, 0, stream>>>(bedges, bstart, dis, hw2, b2, out, N);
}

// Round 4
// 484.825 us; speedup vs baseline: 3.4314x; 3.4314x over previous
//
#include <hip/hip_runtime.h>
#include <stdint.h>

// GCN 2-layer forward: two-level counting sort (bucket scatter -> per-bucket
// LDS sort) builds exact dst-sorted CSR, then pull-mode gathers (no global
// fp32 atomics, no scattered 4B writes outside a 64KB span).

#define TPB 256
#define TILE 512           // nodes per bucket
#define TSH  9
#define MAXB 512           // supports N <= 262144 (src must fit 18 bits)

__global__ void k_zero_i(int* __restrict__ p, int m) {
    int i = blockIdx.x * TPB + threadIdx.x;
    if (i < m) p[i] = 0;
}

// global per-bucket histogram (LDS-staged)
__global__ __launch_bounds__(TPB) void k_bhist(const int* __restrict__ dst,
                                               int* __restrict__ bcnt, int e, int nb) {
    __shared__ int h[MAXB];
    for (int i = threadIdx.x; i < MAXB; i += TPB) h[i] = 0;
    __syncthreads();
    int stride = gridDim.x * TPB;
    for (int i = blockIdx.x * TPB + threadIdx.x; i < e; i += stride)
        atomicAdd(&h[dst[i] >> TSH], 1);
    __syncthreads();
    for (int i = threadIdx.x; i < nb; i += TPB)
        if (h[i]) atomicAdd(&bcnt[i], h[i]);
}

// single-block exclusive scan of bucket counts -> bstart, init bcursor
__global__ void k_bscan(const int* __restrict__ bcnt, int* __restrict__ bstart,
                        int* __restrict__ bcursor, int nb) {
    __shared__ int buf[2][MAXB];
    int t = threadIdx.x;            // 512 threads
    int v = (t < nb) ? bcnt[t] : 0;
    buf[0][t] = v;
    __syncthreads();
    int cur = 0;
#pragma unroll
    for (int off = 1; off < MAXB; off <<= 1) {
        int nv = buf[cur][t] + (t >= off ? buf[cur][t - off] : 0);
        buf[cur ^ 1][t] = nv;
        __syncthreads();
        cur ^= 1;
    }
    int excl = buf[cur][t] - v;
    if (t < nb) { bstart[t] = excl; bcursor[t] = excl; }
    if (t == nb - 1) bstart[nb] = excl + v;
}

// bucket scatter: contiguous runs into bedges, packed (local_dst<<18)|src
__global__ __launch_bounds__(1024) void k_bscatter(const int* __restrict__ src,
                                                   const int* __restrict__ dst,
                                                   int* __restrict__ bcursor,
                                                   uint32_t* __restrict__ bedges,
                                                   int e, int chunk) {
    __shared__ int hcnt[MAXB];
    __shared__ int hbase[MAXB];
    __shared__ int hpos[MAXB];
    int t = threadIdx.x;
    for (int i = t; i < MAXB; i += 1024) { hcnt[i] = 0; hpos[i] = 0; }
    __syncthreads();

    int e0 = blockIdx.x * chunk;
    int e1 = min(e0 + chunk, e);

    for (int i = e0 + t; i < e1; i += 1024)
        atomicAdd(&hcnt[dst[i] >> TSH], 1);
    __syncthreads();
    for (int i = t; i < MAXB; i += 1024)
        if (hcnt[i]) hbase[i] = atomicAdd(&bcursor[i], hcnt[i]);
    __syncthreads();
    for (int i = e0 + t; i < e1; i += 1024) {
        int d = dst[i];
        int b = d >> TSH;
        int lp = atomicAdd(&hpos[b], 1);
        bedges[hbase[b] + lp] = ((uint32_t)(d & (TILE - 1)) << 18) | (uint32_t)src[i];
    }
}

// per-bucket counting sort: bedges segment -> csr (src only, exact dst order).
// Also emits node_start[d] and dis[d]. Writes stay within the bucket's span.
__global__ __launch_bounds__(1024) void k_sort(const uint32_t* __restrict__ bedges,
                                               const int* __restrict__ bstart,
                                               uint32_t* __restrict__ csr,
                                               int* __restrict__ node_start,
                                               float* __restrict__ dis, int n) {
    __shared__ int hist[TILE];
    __shared__ int sb[2][TILE];
    __shared__ int curp[TILE];
    int t = threadIdx.x;            // 1024 threads
    int b = blockIdx.x;
    int s0 = bstart[b], s1 = bstart[b + 1];

    if (t < TILE) hist[t] = 0;
    __syncthreads();
    for (int i = s0 + t; i < s1; i += 1024)
        atomicAdd(&hist[bedges[i] >> 18], 1);
    __syncthreads();

    if (t < TILE) sb[0][t] = hist[t];
    __syncthreads();
    int cur = 0;
#pragma unroll
    for (int off = 1; off < TILE; off <<= 1) {
        if (t < TILE) {
            int nv = sb[cur][t] + (t >= off ? sb[cur][t - off] : 0);
            sb[cur ^ 1][t] = nv;
        }
        __syncthreads();
        cur ^= 1;
    }
    if (t < TILE) {
        int ex = sb[cur][t] - hist[t];          // exclusive
        curp[t] = ex;
        int d = (b << TSH) + t;
        if (d <= n) node_start[d] = s0 + ex;    // d==n covered by last bucket
        if (d < n)  dis[d] = rsqrtf((float)hist[t] + 1.0f);
    }
    __syncthreads();

    for (int i = s0 + t; i < s1; i += 1024) {
        uint32_t p = bedges[i];
        int ld = (int)(p >> 18);
        int pos = atomicAdd(&curp[ld], 1);
        csr[s0 + pos] = p & 0x3FFFFu;
    }
}

// h1w = (x @ W1) * dis[row]
__global__ __launch_bounds__(TPB) void k_gemm1h(const float* __restrict__ x,
                                                const float* __restrict__ W1,
                                                const float* __restrict__ dis,
                                                float* __restrict__ h1w, int n) {
    __shared__ float w[128 * 32];
    for (int i = threadIdx.x; i < 128 * 32; i += TPB) w[i] = W1[i];
    __syncthreads();

    int lane = threadIdx.x & 31;
    int row  = blockIdx.x * 8 + (threadIdx.x >> 5);
    if (row >= n) return;

    const float4* xr = (const float4*)(x + (size_t)row * 128);
    float acc = 0.0f;
#pragma unroll
    for (int k4 = 0; k4 < 32; ++k4) {
        float4 xv = xr[k4];
        acc = fmaf(xv.x, w[(k4 * 4 + 0) * 32 + lane], acc);
        acc = fmaf(xv.y, w[(k4 * 4 + 1) * 32 + lane], acc);
        acc = fmaf(xv.z, w[(k4 * 4 + 2) * 32 + lane], acc);
        acc = fmaf(xv.w, w[(k4 * 4 + 3) * 32 + lane], acc);
    }
    h1w[(size_t)row * 32 + lane] = acc * dis[row];
}

// Layer1 gather + fused self-loop/bias/relu/dropout/W2; hw2 = (v@W2)*dis[d]
__global__ __launch_bounds__(TPB) void k_gather1(const int* __restrict__ node_start,
                                                 const uint32_t* __restrict__ csr,
                                                 const float* __restrict__ dis,
                                                 const float* __restrict__ h1w,
                                                 const float* __restrict__ b1,
                                                 const float* __restrict__ drop_u,
                                                 const float* __restrict__ W2,
                                                 float* __restrict__ hw2, int n) {
    int t = blockIdx.x * TPB + threadIdx.x;
    int d = t >> 5, c = t & 31;
    if (d >= n) return;

    int e  = node_start[d];
    int e1 = node_start[d + 1];

    float acc = 0.0f;
    for (; e + 3 < e1; e += 4) {
        int s0 = csr[e], s1 = csr[e + 1], s2 = csr[e + 2], s3 = csr[e + 3];
        float v0 = h1w[(size_t)s0 * 32 + c];
        float v1 = h1w[(size_t)s1 * 32 + c];
        float v2 = h1w[(size_t)s2 * 32 + c];
        float v3 = h1w[(size_t)s3 * 32 + c];
        acc += (v0 + v1) + (v2 + v3);
    }
    for (; e < e1; ++e) acc += h1w[(size_t)csr[e] * 32 + c];

    float dd = dis[d];
    float v = dd * (acc + h1w[(size_t)d * 32 + c]) + b1[c];
    v = fmaxf(v, 0.0f);
    v = (drop_u[(size_t)d * 32 + c] > 0.5f) ? v * 2.0f : 0.0f;

    float p0 = v * W2[c * 2 + 0];
    float p1 = v * W2[c * 2 + 1];
#pragma unroll
    for (int off = 16; off >= 1; off >>= 1) {
        p0 += __shfl_xor(p0, off, 32);
        p1 += __shfl_xor(p1, off, 32);
    }
    if (c == 0) {
        float2 o; o.x = p0 * dd; o.y = p1 * dd;
        ((float2*)hw2)[d] = o;
    }
}

// Layer2 gather: out[d] = dis[d]*(sum_s hw2[s] + hw2[d]) + b2
__global__ __launch_bounds__(TPB) void k_gather2(const int* __restrict__ node_start,
                                                 const uint32_t* __restrict__ csr,
                                                 const float* __restrict__ dis,
                                                 const float* __restrict__ hw2,
                                                 const float* __restrict__ b2,
                                                 float* __restrict__ out, int n) {
    int t = blockIdx.x * TPB + threadIdx.x;
    int d = t >> 5, lane = t & 31;
    if (d >= n) return;

    int e0 = node_start[d];
    int e1 = node_start[d + 1];

    float a0 = 0.0f, a1 = 0.0f;
    for (int e = e0 + lane; e < e1; e += 32) {
        int s = csr[e];
        float2 hv = ((const float2*)hw2)[s];
        a0 += hv.x;
        a1 += hv.y;
    }
#pragma unroll
    for (int off = 16; off >= 1; off >>= 1) {
        a0 += __shfl_xor(a0, off, 32);
        a1 += __shfl_xor(a1, off, 32);
    }
    if (lane == 0) {
        float dd = dis[d];
        float2 hv = ((const float2*)hw2)[d];
        out[(size_t)d * 2 + 0] = dd * (a0 + hv.x) + b2[0];
        out[(size_t)d * 2 + 1] = dd * (a1 + hv.y) + b2[1];
    }
}

extern "C" void kernel_launch(void* const* d_in, const int* in_sizes, int n_in,
                              void* d_out, int out_size, void* d_ws, size_t ws_size,
                              hipStream_t stream) {
    const float* x     = (const float*)d_in[0];
    const int*   ei    = (const int*)d_in[1];
    const float* W1    = (const float*)d_in[2];
    const float* b1    = (const float*)d_in[3];
    const float* W2    = (const float*)d_in[4];
    const float* b2    = (const float*)d_in[5];
    const float* dropu = (const float*)d_in[6];
    float* out = (float*)d_out;

    const int N = in_sizes[0] / 128;
    const int E = in_sizes[1] / 2;
    const int* src = ei;
    const int* dst = ei + E;

    const int NB = (N + TILE - 1) >> TSH;     // 391 for N=200000

    // ws: dis f32[N] | h1w f32[N*32] | hw2 f32[N*2] | node_start i32[N+1] |
    //     bcnt i32[MAXB] | bstart i32[MAXB+1] | bcursor i32[MAXB] |
    //     bedges u32[E] | csr u32[E]
    float* dis = (float*)d_ws;
    float* h1w = dis + N;
    float* hw2 = h1w + (size_t)N * 32;
    int* node_start = (int*)(hw2 + (size_t)N * 2);
    int* bcnt    = node_start + (N + 1);
    int* bstart  = bcnt + MAXB;
    int* bcursor = bstart + (MAXB + 1);
    uint32_t* bedges = (uint32_t*)(bcursor + MAXB);
    uint32_t* csr    = bedges + E;

    const int chunk = (E + NB - 1) / NB;
    const int gG = (N * 32 + TPB - 1) / TPB;  // 32 lanes per node

    k_zero_i  <<<(MAXB + TPB - 1) / TPB, TPB, 0, stream>>>(bcnt, MAXB);
    k_bhist   <<<1024, TPB, 0, stream>>>(dst, bcnt, E, NB);
    k_bscan   <<<1, MAXB, 0, stream>>>(bcnt, bstart, bcursor, NB);
    k_bscatter<<<NB, 1024, 0, stream>>>(src, dst, bcursor, bedges, E, chunk);
    k_sort    <<<NB, 1024, 0, stream>>>(bedges, bstart, csr, node_start, dis, N);
    k_gemm1h  <<<(N + 7) / 8, TPB, 0, stream>>>(x, W1, dis, h1w, N);
    k_gather1 <<<gG, TPB, 0, stream>>>(node_start, csr, dis, h1w, b1, dropu, W2, hw2, N);
    k_gather2 <<<gG, TPB, 0, stream>>>(node_start, csr, dis, hw2, b2, out, N);
}

// Round 5
// 480.846 us; speedup vs baseline: 3.4598x; 1.0083x over previous
//
#include <hip/hip_runtime.h>
#include <hip/hip_fp16.h>
#include <stdint.h>

// GCN 2-layer forward: two-level counting sort -> dst-sorted CSR -> pull gathers.
// h1w stored fp16 to halve gather traffic. W1 kept in registers in the GEMM.

#define TPB 256
#define TILE 512           // nodes per bucket
#define TSH  9
#define MAXB 512           // supports N <= 262144 (src must fit 18 bits)
#define GRPB 128           // gemm rows per block
#define GROWS 16           // gemm rows per 32-lane group

__global__ void k_zero_i(int* __restrict__ p, int m) {
    int i = blockIdx.x * TPB + threadIdx.x;
    if (i < m) p[i] = 0;
}

// global per-bucket histogram (LDS-staged)
__global__ __launch_bounds__(TPB) void k_bhist(const int* __restrict__ dst,
                                               int* __restrict__ bcnt, int e, int nb) {
    __shared__ int h[MAXB];
    for (int i = threadIdx.x; i < MAXB; i += TPB) h[i] = 0;
    __syncthreads();
    int stride = gridDim.x * TPB;
    for (int i = blockIdx.x * TPB + threadIdx.x; i < e; i += stride)
        atomicAdd(&h[dst[i] >> TSH], 1);
    __syncthreads();
    for (int i = threadIdx.x; i < nb; i += TPB)
        if (h[i]) atomicAdd(&bcnt[i], h[i]);
}

// single-block exclusive scan of bucket counts -> bstart, init bcursor
__global__ void k_bscan(const int* __restrict__ bcnt, int* __restrict__ bstart,
                        int* __restrict__ bcursor, int nb) {
    __shared__ int buf[2][MAXB];
    int t = threadIdx.x;            // 512 threads
    int v = (t < nb) ? bcnt[t] : 0;
    buf[0][t] = v;
    __syncthreads();
    int cur = 0;
#pragma unroll
    for (int off = 1; off < MAXB; off <<= 1) {
        int nv = buf[cur][t] + (t >= off ? buf[cur][t - off] : 0);
        buf[cur ^ 1][t] = nv;
        __syncthreads();
        cur ^= 1;
    }
    int excl = buf[cur][t] - v;
    if (t < nb) { bstart[t] = excl; bcursor[t] = excl; }
    if (t == nb - 1) bstart[nb] = excl + v;
}

// bucket scatter: contiguous runs into bedges, packed (local_dst<<18)|src
__global__ __launch_bounds__(1024) void k_bscatter(const int* __restrict__ src,
                                                   const int* __restrict__ dst,
                                                   int* __restrict__ bcursor,
                                                   uint32_t* __restrict__ bedges,
                                                   int e, int chunk) {
    __shared__ int hcnt[MAXB];
    __shared__ int hbase[MAXB];
    __shared__ int hpos[MAXB];
    int t = threadIdx.x;
    for (int i = t; i < MAXB; i += 1024) { hcnt[i] = 0; hpos[i] = 0; }
    __syncthreads();

    int e0 = blockIdx.x * chunk;
    int e1 = min(e0 + chunk, e);

    for (int i = e0 + t; i < e1; i += 1024)
        atomicAdd(&hcnt[dst[i] >> TSH], 1);
    __syncthreads();
    for (int i = t; i < MAXB; i += 1024)
        if (hcnt[i]) hbase[i] = atomicAdd(&bcursor[i], hcnt[i]);
    __syncthreads();
    for (int i = e0 + t; i < e1; i += 1024) {
        int d = dst[i];
        int b = d >> TSH;
        int lp = atomicAdd(&hpos[b], 1);
        bedges[hbase[b] + lp] = ((uint32_t)(d & (TILE - 1)) << 18) | (uint32_t)src[i];
    }
}

// per-bucket counting sort: bedges segment -> csr (src only, exact dst order).
// Also emits node_start[d] and dis[d].
__global__ __launch_bounds__(1024) void k_sort(const uint32_t* __restrict__ bedges,
                                               const int* __restrict__ bstart,
                                               uint32_t* __restrict__ csr,
                                               int* __restrict__ node_start,
                                               float* __restrict__ dis, int n) {
    __shared__ int hist[TILE];
    __shared__ int sb[2][TILE];
    __shared__ int curp[TILE];
    int t = threadIdx.x;            // 1024 threads
    int b = blockIdx.x;
    int s0 = bstart[b], s1 = bstart[b + 1];

    if (t < TILE) hist[t] = 0;
    __syncthreads();
    for (int i = s0 + t; i < s1; i += 1024)
        atomicAdd(&hist[bedges[i] >> 18], 1);
    __syncthreads();

    if (t < TILE) sb[0][t] = hist[t];
    __syncthreads();
    int cur = 0;
#pragma unroll
    for (int off = 1; off < TILE; off <<= 1) {
        if (t < TILE) {
            int nv = sb[cur][t] + (t >= off ? sb[cur][t - off] : 0);
            sb[cur ^ 1][t] = nv;
        }
        __syncthreads();
        cur ^= 1;
    }
    if (t < TILE) {
        int ex = sb[cur][t] - hist[t];          // exclusive
        curp[t] = ex;
        int d = (b << TSH) + t;
        if (d <= n) node_start[d] = s0 + ex;
        if (d < n)  dis[d] = rsqrtf((float)hist[t] + 1.0f);
    }
    __syncthreads();

    for (int i = s0 + t; i < s1; i += 1024) {
        uint32_t p = bedges[i];
        int ld = (int)(p >> 18);
        int pos = atomicAdd(&curp[ld], 1);
        csr[s0 + pos] = p & 0x3FFFFu;
    }
}

// h1w = fp16( (x @ W1) * dis[row] ).  W1 column held in 128 registers per lane.
// 256 threads = 8 groups x 32 lanes; each group does GROWS rows, 4 in flight.
__global__ __launch_bounds__(TPB) void k_gemm1h(const float* __restrict__ x,
                                                const float* __restrict__ W1,
                                                const float* __restrict__ dis,
                                                __half* __restrict__ h1w, int n) {
    int lane = threadIdx.x & 31;
    int g    = threadIdx.x >> 5;

    float w[128];
#pragma unroll
    for (int k = 0; k < 128; ++k) w[k] = W1[k * 32 + lane];   // coalesced across lanes

    int base = blockIdx.x * GRPB + g * GROWS;

#pragma unroll
    for (int r = 0; r < GROWS; r += 4) {
        int row = base + r;
        if (row >= n) break;
        if (row + 3 < n) {
            const float4* x0 = (const float4*)(x + (size_t)row * 128);
            const float4* x1 = x0 + 32;
            const float4* x2 = x1 + 32;
            const float4* x3 = x2 + 32;
            float a0 = 0.f, a1 = 0.f, a2 = 0.f, a3 = 0.f;
#pragma unroll
            for (int k4 = 0; k4 < 32; ++k4) {
                float4 v0 = x0[k4], v1 = x1[k4], v2 = x2[k4], v3 = x3[k4];
                a0 = fmaf(v0.x, w[k4 * 4 + 0], a0);
                a0 = fmaf(v0.y, w[k4 * 4 + 1], a0);
                a0 = fmaf(v0.z, w[k4 * 4 + 2], a0);
                a0 = fmaf(v0.w, w[k4 * 4 + 3], a0);
                a1 = fmaf(v1.x, w[k4 * 4 + 0], a1);
                a1 = fmaf(v1.y, w[k4 * 4 + 1], a1);
                a1 = fmaf(v1.z, w[k4 * 4 + 2], a1);
                a1 = fmaf(v1.w, w[k4 * 4 + 3], a1);
                a2 = fmaf(v2.x, w[k4 * 4 + 0], a2);
                a2 = fmaf(v2.y, w[k4 * 4 + 1], a2);
                a2 = fmaf(v2.z, w[k4 * 4 + 2], a2);
                a2 = fmaf(v2.w, w[k4 * 4 + 3], a2);
                a3 = fmaf(v3.x, w[k4 * 4 + 0], a3);
                a3 = fmaf(v3.y, w[k4 * 4 + 1], a3);
                a3 = fmaf(v3.z, w[k4 * 4 + 2], a3);
                a3 = fmaf(v3.w, w[k4 * 4 + 3], a3);
            }
            h1w[(size_t)(row + 0) * 32 + lane] = __float2half(a0 * dis[row + 0]);
            h1w[(size_t)(row + 1) * 32 + lane] = __float2half(a1 * dis[row + 1]);
            h1w[(size_t)(row + 2) * 32 + lane] = __float2half(a2 * dis[row + 2]);
            h1w[(size_t)(row + 3) * 32 + lane] = __float2half(a3 * dis[row + 3]);
        } else {
            for (int rr = 0; rr < 4; ++rr) {
                int rowi = row + rr;
                if (rowi >= n) break;
                const float4* x0 = (const float4*)(x + (size_t)rowi * 128);
                float a0 = 0.f;
#pragma unroll
                for (int k4 = 0; k4 < 32; ++k4) {
                    float4 v0 = x0[k4];
                    a0 = fmaf(v0.x, w[k4 * 4 + 0], a0);
                    a0 = fmaf(v0.y, w[k4 * 4 + 1], a0);
                    a0 = fmaf(v0.z, w[k4 * 4 + 2], a0);
                    a0 = fmaf(v0.w, w[k4 * 4 + 3], a0);
                }
                h1w[(size_t)rowi * 32 + lane] = __float2half(a0 * dis[rowi]);
            }
        }
    }
}

// Layer1 gather (fp16 rows) + fused self-loop/bias/relu/dropout/W2; hw2=(v@W2)*dis[d]
__global__ __launch_bounds__(TPB) void k_gather1(const int* __restrict__ node_start,
                                                 const uint32_t* __restrict__ csr,
                                                 const float* __restrict__ dis,
                                                 const __half* __restrict__ h1w,
                                                 const float* __restrict__ b1,
                                                 const float* __restrict__ drop_u,
                                                 const float* __restrict__ W2,
                                                 float* __restrict__ hw2, int n) {
    int t = blockIdx.x * TPB + threadIdx.x;
    int d = t >> 5, c = t & 31;
    if (d >= n) return;

    int e  = node_start[d];
    int e1 = node_start[d + 1];

    float acc = 0.0f;
    for (; e + 7 < e1; e += 8) {
        int s0 = csr[e],     s1 = csr[e + 1], s2 = csr[e + 2], s3 = csr[e + 3];
        int s4 = csr[e + 4], s5 = csr[e + 5], s6 = csr[e + 6], s7 = csr[e + 7];
        float v0 = __half2float(h1w[(size_t)s0 * 32 + c]);
        float v1 = __half2float(h1w[(size_t)s1 * 32 + c]);
        float v2 = __half2float(h1w[(size_t)s2 * 32 + c]);
        float v3 = __half2float(h1w[(size_t)s3 * 32 + c]);
        float v4 = __half2float(h1w[(size_t)s4 * 32 + c]);
        float v5 = __half2float(h1w[(size_t)s5 * 32 + c]);
        float v6 = __half2float(h1w[(size_t)s6 * 32 + c]);
        float v7 = __half2float(h1w[(size_t)s7 * 32 + c]);
        acc += ((v0 + v1) + (v2 + v3)) + ((v4 + v5) + (v6 + v7));
    }
    for (; e < e1; ++e) acc += __half2float(h1w[(size_t)csr[e] * 32 + c]);

    float dd = dis[d];
    float selfv = __half2float(h1w[(size_t)d * 32 + c]);
    float v = dd * (acc + selfv) + b1[c];
    v = fmaxf(v, 0.0f);
    v = (drop_u[(size_t)d * 32 + c] > 0.5f) ? v * 2.0f : 0.0f;

    float p0 = v * W2[c * 2 + 0];
    float p1 = v * W2[c * 2 + 1];
#pragma unroll
    for (int off = 16; off >= 1; off >>= 1) {
        p0 += __shfl_xor(p0, off, 32);
        p1 += __shfl_xor(p1, off, 32);
    }
    if (c == 0) {
        float2 o; o.x = p0 * dd; o.y = p1 * dd;
        ((float2*)hw2)[d] = o;
    }
}

// Layer2 gather: out[d] = dis[d]*(sum_s hw2[s] + hw2[d]) + b2
__global__ __launch_bounds__(TPB) void k_gather2(const int* __restrict__ node_start,
                                                 const uint32_t* __restrict__ csr,
                                                 const float* __restrict__ dis,
                                                 const float* __restrict__ hw2,
                                                 const float* __restrict__ b2,
                                                 float* __restrict__ out, int n) {
    int t = blockIdx.x * TPB + threadIdx.x;
    int d = t >> 5, lane = t & 31;
    if (d >= n) return;

    int e0 = node_start[d];
    int e1 = node_start[d + 1];

    float a0 = 0.0f, a1 = 0.0f;
    for (int e = e0 + lane; e < e1; e += 32) {
        int s = csr[e];
        float2 hv = ((const float2*)hw2)[s];
        a0 += hv.x;
        a1 += hv.y;
    }
#pragma unroll
    for (int off = 16; off >= 1; off >>= 1) {
        a0 += __shfl_xor(a0, off, 32);
        a1 += __shfl_xor(a1, off, 32);
    }
    if (lane == 0) {
        float dd = dis[d];
        float2 hv = ((const float2*)hw2)[d];
        out[(size_t)d * 2 + 0] = dd * (a0 + hv.x) + b2[0];
        out[(size_t)d * 2 + 1] = dd * (a1 + hv.y) + b2[1];
    }
}

extern "C" void kernel_launch(void* const* d_in, const int* in_sizes, int n_in,
                              void* d_out, int out_size, void* d_ws, size_t ws_size,
                              hipStream_t stream) {
    const float* x     = (const float*)d_in[0];
    const int*   ei    = (const int*)d_in[1];
    const float* W1    = (const float*)d_in[2];
    const float* b1    = (const float*)d_in[3];
    const float* W2    = (const float*)d_in[4];
    const float* b2    = (const float*)d_in[5];
    const float* dropu = (const float*)d_in[6];
    float* out = (float*)d_out;

    const int N = in_sizes[0] / 128;
    const int E = in_sizes[1] / 2;
    const int* src = ei;
    const int* dst = ei + E;

    const int NB = (N + TILE - 1) >> TSH;     // 391 for N=200000

    // ws: dis f32[N] | hw2 f32[2N] | node_start i32[N+1] | bcnt i32[MAXB] |
    //     bstart i32[MAXB+1] | bcursor i32[MAXB] | bedges u32[E] | csr u32[E] |
    //     h1w fp16[32N]
    float* dis = (float*)d_ws;
    float* hw2 = dis + N;
    int* node_start = (int*)(hw2 + (size_t)N * 2);
    int* bcnt    = node_start + (N + 1);
    int* bstart  = bcnt + MAXB;
    int* bcursor = bstart + (MAXB + 1);
    uint32_t* bedges = (uint32_t*)(bcursor + MAXB);
    uint32_t* csr    = bedges + E;
    __half* h1w = (__half*)(csr + E);

    const int chunk = (E + NB - 1) / NB;
    const int gG = (N * 32 + TPB - 1) / TPB;  // 32 lanes per node

    k_zero_i  <<<(MAXB + TPB - 1) / TPB, TPB, 0, stream>>>(bcnt, MAXB);
    k_bhist   <<<1024, TPB, 0, stream>>>(dst, bcnt, E, NB);
    k_bscan   <<<1, MAXB, 0, stream>>>(bcnt, bstart, bcursor, NB);
    k_bscatter<<<NB, 1024, 0, stream>>>(src, dst, bcursor, bedges, E, chunk);
    k_sort    <<<NB, 1024, 0, stream>>>(bedges, bstart, csr, node_start, dis, N);
    k_gemm1h  <<<(N + GRPB - 1) / GRPB, TPB, 0, stream>>>(x, W1, dis, h1w, N);
    k_gather1 <<<gG, TPB, 0, stream>>>(node_start, csr, dis, h1w, b1, dropu, W2, hw2, N);
    k_gather2 <<<gG, TPB, 0, stream>>>(node_start, csr, dis, hw2, b2, out, N);
}

// Round 6
// 442.373 us; speedup vs baseline: 3.7607x; 1.0870x over previous
//
#include <hip/hip_runtime.h>
#include <hip/hip_fp16.h>
#include <stdint.h>

// GCN 2-layer forward: two-level counting sort -> dst-sorted CSR -> pull gathers.
// h1w stored fp16. GEMM: W1 in LDS (conflict-free [k][lane]), 4 rows in flight
// per 32-lane group so 4 ds_read_b32 feed 16 FMAs (round-4 was 1:1 -> LDS-bound;
// round-5 register-W spilled to scratch: VGPR 88 + 13.9MB scratch writes).

#define TPB 256
#define TILE 512           // nodes per bucket
#define TSH  9
#define MAXB 512           // supports N <= 262144 (src must fit 18 bits)

__global__ void k_zero_i(int* __restrict__ p, int m) {
    int i = blockIdx.x * TPB + threadIdx.x;
    if (i < m) p[i] = 0;
}

// global per-bucket histogram (LDS-staged)
__global__ __launch_bounds__(TPB) void k_bhist(const int* __restrict__ dst,
                                               int* __restrict__ bcnt, int e, int nb) {
    __shared__ int h[MAXB];
    for (int i = threadIdx.x; i < MAXB; i += TPB) h[i] = 0;
    __syncthreads();
    int stride = gridDim.x * TPB;
    for (int i = blockIdx.x * TPB + threadIdx.x; i < e; i += stride)
        atomicAdd(&h[dst[i] >> TSH], 1);
    __syncthreads();
    for (int i = threadIdx.x; i < nb; i += TPB)
        if (h[i]) atomicAdd(&bcnt[i], h[i]);
}

// single-block exclusive scan of bucket counts -> bstart, init bcursor
__global__ void k_bscan(const int* __restrict__ bcnt, int* __restrict__ bstart,
                        int* __restrict__ bcursor, int nb) {
    __shared__ int buf[2][MAXB];
    int t = threadIdx.x;            // 512 threads
    int v = (t < nb) ? bcnt[t] : 0;
    buf[0][t] = v;
    __syncthreads();
    int cur = 0;
#pragma unroll
    for (int off = 1; off < MAXB; off <<= 1) {
        int nv = buf[cur][t] + (t >= off ? buf[cur][t - off] : 0);
        buf[cur ^ 1][t] = nv;
        __syncthreads();
        cur ^= 1;
    }
    int excl = buf[cur][t] - v;
    if (t < nb) { bstart[t] = excl; bcursor[t] = excl; }
    if (t == nb - 1) bstart[nb] = excl + v;
}

// bucket scatter: contiguous runs into bedges, packed (local_dst<<18)|src
__global__ __launch_bounds__(1024) void k_bscatter(const int* __restrict__ src,
                                                   const int* __restrict__ dst,
                                                   int* __restrict__ bcursor,
                                                   uint32_t* __restrict__ bedges,
                                                   int e, int chunk) {
    __shared__ int hcnt[MAXB];
    __shared__ int hbase[MAXB];
    __shared__ int hpos[MAXB];
    int t = threadIdx.x;
    for (int i = t; i < MAXB; i += 1024) { hcnt[i] = 0; hpos[i] = 0; }
    __syncthreads();

    int e0 = blockIdx.x * chunk;
    int e1 = min(e0 + chunk, e);

    for (int i = e0 + t; i < e1; i += 1024)
        atomicAdd(&hcnt[dst[i] >> TSH], 1);
    __syncthreads();
    for (int i = t; i < MAXB; i += 1024)
        if (hcnt[i]) hbase[i] = atomicAdd(&bcursor[i], hcnt[i]);
    __syncthreads();
    for (int i = e0 + t; i < e1; i += 1024) {
        int d = dst[i];
        int b = d >> TSH;
        int lp = atomicAdd(&hpos[b], 1);
        bedges[hbase[b] + lp] = ((uint32_t)(d & (TILE - 1)) << 18) | (uint32_t)src[i];
    }
}

// per-bucket counting sort: bedges segment -> csr (src only, exact dst order).
// Also emits node_start[d] and dis[d].
__global__ __launch_bounds__(1024) void k_sort(const uint32_t* __restrict__ bedges,
                                               const int* __restrict__ bstart,
                                               uint32_t* __restrict__ csr,
                                               int* __restrict__ node_start,
                                               float* __restrict__ dis, int n) {
    __shared__ int hist[TILE];
    __shared__ int sb[2][TILE];
    __shared__ int curp[TILE];
    int t = threadIdx.x;            // 1024 threads
    int b = blockIdx.x;
    int s0 = bstart[b], s1 = bstart[b + 1];

    if (t < TILE) hist[t] = 0;
    __syncthreads();
    for (int i = s0 + t; i < s1; i += 1024)
        atomicAdd(&hist[bedges[i] >> 18], 1);
    __syncthreads();

    if (t < TILE) sb[0][t] = hist[t];
    __syncthreads();
    int cur = 0;
#pragma unroll
    for (int off = 1; off < TILE; off <<= 1) {
        if (t < TILE) {
            int nv = sb[cur][t] + (t >= off ? sb[cur][t - off] : 0);
            sb[cur ^ 1][t] = nv;
        }
        __syncthreads();
        cur ^= 1;
    }
    if (t < TILE) {
        int ex = sb[cur][t] - hist[t];          // exclusive
        curp[t] = ex;
        int d = (b << TSH) + t;
        if (d <= n) node_start[d] = s0 + ex;
        if (d < n)  dis[d] = rsqrtf((float)hist[t] + 1.0f);
    }
    __syncthreads();

    for (int i = s0 + t; i < s1; i += 1024) {
        uint32_t p = bedges[i];
        int ld = (int)(p >> 18);
        int pos = atomicAdd(&curp[ld], 1);
        csr[s0 + pos] = p & 0x3FFFFu;
    }
}

// h1w = fp16( (x @ W1) * dis[row] ).
// W1 in LDS [k][lane] (consecutive across lanes -> conflict-free b32 reads).
// 256 threads = 8 groups x 32 lanes; each group does 8 rows, 4 in flight:
// 4 ds_read_b32 (shared w values) feed 16 FMAs.
__global__ __launch_bounds__(TPB) void k_gemm1h(const float* __restrict__ x,
                                                const float* __restrict__ W1,
                                                const float* __restrict__ dis,
                                                __half* __restrict__ h1w, int n) {
    __shared__ float w[128 * 32];
    for (int i = threadIdx.x; i < 128 * 32; i += TPB) w[i] = W1[i];
    __syncthreads();

    int lane = threadIdx.x & 31;
    int g    = threadIdx.x >> 5;
    int base = blockIdx.x * 64 + g * 8;

    for (int rb = 0; rb < 8; rb += 4) {
        int row = base + rb;
        if (row >= n) break;
        if (row + 3 < n) {
            const float4* x0 = (const float4*)(x + (size_t)row * 128);
            const float4* x1 = x0 + 32;
            const float4* x2 = x1 + 32;
            const float4* x3 = x2 + 32;
            float a0 = 0.f, a1 = 0.f, a2 = 0.f, a3 = 0.f;
#pragma unroll
            for (int k4 = 0; k4 < 32; ++k4) {
                float4 v0 = x0[k4], v1 = x1[k4], v2 = x2[k4], v3 = x3[k4];
                float w0 = w[(k4 * 4 + 0) * 32 + lane];
                float w1_ = w[(k4 * 4 + 1) * 32 + lane];
                float w2_ = w[(k4 * 4 + 2) * 32 + lane];
                float w3_ = w[(k4 * 4 + 3) * 32 + lane];
                a0 = fmaf(v0.x, w0, a0); a0 = fmaf(v0.y, w1_, a0);
                a0 = fmaf(v0.z, w2_, a0); a0 = fmaf(v0.w, w3_, a0);
                a1 = fmaf(v1.x, w0, a1); a1 = fmaf(v1.y, w1_, a1);
                a1 = fmaf(v1.z, w2_, a1); a1 = fmaf(v1.w, w3_, a1);
                a2 = fmaf(v2.x, w0, a2); a2 = fmaf(v2.y, w1_, a2);
                a2 = fmaf(v2.z, w2_, a2); a2 = fmaf(v2.w, w3_, a2);
                a3 = fmaf(v3.x, w0, a3); a3 = fmaf(v3.y, w1_, a3);
                a3 = fmaf(v3.z, w2_, a3); a3 = fmaf(v3.w, w3_, a3);
            }
            h1w[(size_t)(row + 0) * 32 + lane] = __float2half(a0 * dis[row + 0]);
            h1w[(size_t)(row + 1) * 32 + lane] = __float2half(a1 * dis[row + 1]);
            h1w[(size_t)(row + 2) * 32 + lane] = __float2half(a2 * dis[row + 2]);
            h1w[(size_t)(row + 3) * 32 + lane] = __float2half(a3 * dis[row + 3]);
        } else {
            for (int rr = 0; rr < 4; ++rr) {
                int rowi = row + rr;
                if (rowi >= n) break;
                const float4* x0 = (const float4*)(x + (size_t)rowi * 128);
                float a0 = 0.f;
#pragma unroll
                for (int k4 = 0; k4 < 32; ++k4) {
                    float4 v0 = x0[k4];
                    a0 = fmaf(v0.x, w[(k4 * 4 + 0) * 32 + lane], a0);
                    a0 = fmaf(v0.y, w[(k4 * 4 + 1) * 32 + lane], a0);
                    a0 = fmaf(v0.z, w[(k4 * 4 + 2) * 32 + lane], a0);
                    a0 = fmaf(v0.w, w[(k4 * 4 + 3) * 32 + lane], a0);
                }
                h1w[(size_t)rowi * 32 + lane] = __float2half(a0 * dis[rowi]);
            }
        }
    }
}

// Layer1 gather (fp16 rows) + fused self-loop/bias/relu/dropout/W2; hw2=(v@W2)*dis[d]
__global__ __launch_bounds__(TPB) void k_gather1(const int* __restrict__ node_start,
                                                 const uint32_t* __restrict__ csr,
                                                 const float* __restrict__ dis,
                                                 const __half* __restrict__ h1w,
                                                 const float* __restrict__ b1,
                                                 const float* __restrict__ drop_u,
                                                 const float* __restrict__ W2,
                                                 float* __restrict__ hw2, int n) {
    int t = blockIdx.x * TPB + threadIdx.x;
    int d = t >> 5, c = t & 31;
    if (d >= n) return;

    int e  = node_start[d];
    int e1 = node_start[d + 1];

    float acc = 0.0f;
    for (; e + 7 < e1; e += 8) {
        int s0 = csr[e],     s1 = csr[e + 1], s2 = csr[e + 2], s3 = csr[e + 3];
        int s4 = csr[e + 4], s5 = csr[e + 5], s6 = csr[e + 6], s7 = csr[e + 7];
        float v0 = __half2float(h1w[(size_t)s0 * 32 + c]);
        float v1 = __half2float(h1w[(size_t)s1 * 32 + c]);
        float v2 = __half2float(h1w[(size_t)s2 * 32 + c]);
        float v3 = __half2float(h1w[(size_t)s3 * 32 + c]);
        float v4 = __half2float(h1w[(size_t)s4 * 32 + c]);
        float v5 = __half2float(h1w[(size_t)s5 * 32 + c]);
        float v6 = __half2float(h1w[(size_t)s6 * 32 + c]);
        float v7 = __half2float(h1w[(size_t)s7 * 32 + c]);
        acc += ((v0 + v1) + (v2 + v3)) + ((v4 + v5) + (v6 + v7));
    }
    for (; e < e1; ++e) acc += __half2float(h1w[(size_t)csr[e] * 32 + c]);

    float dd = dis[d];
    float selfv = __half2float(h1w[(size_t)d * 32 + c]);
    float v = dd * (acc + selfv) + b1[c];
    v = fmaxf(v, 0.0f);
    v = (drop_u[(size_t)d * 32 + c] > 0.5f) ? v * 2.0f : 0.0f;

    float p0 = v * W2[c * 2 + 0];
    float p1 = v * W2[c * 2 + 1];
#pragma unroll
    for (int off = 16; off >= 1; off >>= 1) {
        p0 += __shfl_xor(p0, off, 32);
        p1 += __shfl_xor(p1, off, 32);
    }
    if (c == 0) {
        float2 o; o.x = p0 * dd; o.y = p1 * dd;
        ((float2*)hw2)[d] = o;
    }
}

// Layer2 gather: out[d] = dis[d]*(sum_s hw2[s] + hw2[d]) + b2
__global__ __launch_bounds__(TPB) void k_gather2(const int* __restrict__ node_start,
                                                 const uint32_t* __restrict__ csr,
                                                 const float* __restrict__ dis,
                                                 const float* __restrict__ hw2,
                                                 const float* __restrict__ b2,
                                                 float* __restrict__ out, int n) {
    int t = blockIdx.x * TPB + threadIdx.x;
    int d = t >> 5, lane = t & 31;
    if (d >= n) return;

    int e0 = node_start[d];
    int e1 = node_start[d + 1];

    float a0 = 0.0f, a1 = 0.0f;
    for (int e = e0 + lane; e < e1; e += 32) {
        int s = csr[e];
        float2 hv = ((const float2*)hw2)[s];
        a0 += hv.x;
        a1 += hv.y;
    }
#pragma unroll
    for (int off = 16; off >= 1; off >>= 1) {
        a0 += __shfl_xor(a0, off, 32);
        a1 += __shfl_xor(a1, off, 32);
    }
    if (lane == 0) {
        float dd = dis[d];
        float2 hv = ((const float2*)hw2)[d];
        out[(size_t)d * 2 + 0] = dd * (a0 + hv.x) + b2[0];
        out[(size_t)d * 2 + 1] = dd * (a1 + hv.y) + b2[1];
    }
}

extern "C" void kernel_launch(void* const* d_in, const int* in_sizes, int n_in,
                              void* d_out, int out_size, void* d_ws, size_t ws_size,
                              hipStream_t stream) {
    const float* x     = (const float*)d_in[0];
    const int*   ei    = (const int*)d_in[1];
    const float* W1    = (const float*)d_in[2];
    const float* b1    = (const float*)d_in[3];
    const float* W2    = (const float*)d_in[4];
    const float* b2    = (const float*)d_in[5];
    const float* dropu = (const float*)d_in[6];
    float* out = (float*)d_out;

    const int N = in_sizes[0] / 128;
    const int E = in_sizes[1] / 2;
    const int* src = ei;
    const int* dst = ei + E;

    const int NB = (N + TILE - 1) >> TSH;     // 391 for N=200000

    // ws: dis f32[N] | hw2 f32[2N] | node_start i32[N+1] | bcnt i32[MAXB] |
    //     bstart i32[MAXB+1] | bcursor i32[MAXB] | bedges u32[E] | csr u32[E] |
    //     h1w fp16[32N]
    float* dis = (float*)d_ws;
    float* hw2 = dis + N;
    int* node_start = (int*)(hw2 + (size_t)N * 2);
    int* bcnt    = node_start + (N + 1);
    int* bstart  = bcnt + MAXB;
    int* bcursor = bstart + (MAXB + 1);
    uint32_t* bedges = (uint32_t*)(bcursor + MAXB);
    uint32_t* csr    = bedges + E;
    __half* h1w = (__half*)(csr + E);

    const int chunk = (E + NB - 1) / NB;
    const int gG = (N * 32 + TPB - 1) / TPB;  // 32 lanes per node

    k_zero_i  <<<(MAXB + TPB - 1) / TPB, TPB, 0, stream>>>(bcnt, MAXB);
    k_bhist   <<<1024, TPB, 0, stream>>>(dst, bcnt, E, NB);
    k_bscan   <<<1, MAXB, 0, stream>>>(bcnt, bstart, bcursor, NB);
    k_bscatter<<<NB, 1024, 0, stream>>>(src, dst, bcursor, bedges, E, chunk);
    k_sort    <<<NB, 1024, 0, stream>>>(bedges, bstart, csr, node_start, dis, N);
    k_gemm1h  <<<(N + 63) / 64, TPB, 0, stream>>>(x, W1, dis, h1w, N);
    k_gather1 <<<gG, TPB, 0, stream>>>(node_start, csr, dis, h1w, b1, dropu, W2, hw2, N);
    k_gather2 <<<gG, TPB, 0, stream>>>(node_start, csr, dis, hw2, b2, out, N);
}